// Round 2
// baseline (825.440 us; speedup 1.0000x reference)
//
#include <hip/hip_runtime.h>

#define D_INF 64
#define DEF 16   // edge feature dim
#define HF 16    // hidden dim

__device__ __forceinline__ void atomAddF(float* p, float v) {
#if defined(__HIP_DEVICE_COMPILE__)
    unsafeAtomicAdd(p, v);   // hardware global_atomic_add_f32 on gfx950
#else
    atomicAdd(p, v);
#endif
}

// ---------------- prep: xt1 = x @ Wm1[0:64,:], s1 = x @ Ws1 + bs1 ----------------
__global__ __launch_bounds__(256) void k_prep(const float* __restrict__ x,
                                              const float* __restrict__ Wm1,
                                              const float* __restrict__ Ws1,
                                              const float* __restrict__ bs1,
                                              int N, float* __restrict__ xt1, float* __restrict__ s1) {
    int t = blockIdx.x * blockDim.x + threadIdx.x;
    int n = t >> 4, f = t & 15;
    if (n >= N) return;
    const float4* xr4 = (const float4*)(x + (size_t)n * D_INF);
    float am = 0.f, as = bs1[f];
#pragma unroll
    for (int k4 = 0; k4 < 16; k4++) {
        float4 v = xr4[k4];
        int k = 4 * k4;
        am += v.x * Wm1[(k + 0) * HF + f]; as += v.x * Ws1[(k + 0) * HF + f];
        am += v.y * Wm1[(k + 1) * HF + f]; as += v.y * Ws1[(k + 1) * HF + f];
        am += v.z * Wm1[(k + 2) * HF + f]; as += v.z * Ws1[(k + 2) * HF + f];
        am += v.w * Wm1[(k + 3) * HF + f]; as += v.w * Ws1[(k + 3) * HF + f];
    }
    size_t idx = (size_t)n * HF + f;
    xt1[idx] = am;
    s1[idx]  = as;
}

// ---------------- edge pass 1: aggm[dst] += xt1[src] + b1 ; agge[dst] += eattr ----------------
// (edge, feature) layout: wave = 4 edges x 16 features. Each atomic instruction covers
// 4 COMPLETE 64B lines (16 consecutive dwords, one per lane) -> maximal atomic merge.
// eattr stream is fully coalesced (256B/wave), nontemporal (single-use, 205 MB).
__global__ __launch_bounds__(256) void k_edge1(const int* __restrict__ src, const int* __restrict__ dst,
                                               const float* __restrict__ xt1, const float* __restrict__ eattr,
                                               const float* __restrict__ b1,
                                               int E, float* __restrict__ aggm, float* __restrict__ agge) {
    long long t = (long long)blockIdx.x * blockDim.x + threadIdx.x;
    int e = (int)(t >> 4), f = (int)(t & 15);
    if (e >= E) return;
    int s = src[e], d = dst[e];
    float xv = xt1[(size_t)s * HF + f] + b1[f];
    float ev = __builtin_nontemporal_load(eattr + (size_t)e * DEF + f);
    atomAddF(aggm + (size_t)d * HF + f, xv);
    atomAddF(agge + (size_t)d * HF + f, ev);
}

// ---------------- node pass 1: h1 -> xt2, h2base (h1 never materialized) ----------------
// h1 = relu(aggm + agge@Wm1[64:80] + s1)          (deg*b1 folded into aggm)
// xt2 = h1 @ Wm2[0:16] ; h2base = h1@Ws2 + bs2 + agge@Wm2[16:32]
__global__ __launch_bounds__(256) void k_node1(const float* __restrict__ aggm, const float* __restrict__ agge,
                                               const float* __restrict__ s1,
                                               const float* __restrict__ Wm1, const float* __restrict__ Wm2,
                                               const float* __restrict__ Ws2, const float* __restrict__ bs2,
                                               int N, float* __restrict__ xt2, float* __restrict__ h2base) {
    int t = blockIdx.x * blockDim.x + threadIdx.x;
    int n = t >> 4, f = t & 15;
    if (n >= N) return;
    size_t idx = (size_t)n * HF + f;
    float ae  = agge[idx];
    float acc = aggm[idx] + s1[idx];
#pragma unroll
    for (int k = 0; k < HF; k++) {
        acc += __shfl(ae, k, 16) * Wm1[(D_INF + k) * HF + f];
    }
    float h1 = fmaxf(acc, 0.f);
    float xv = 0.f, hb = bs2[f];
#pragma unroll
    for (int k = 0; k < HF; k++) {
        float hk = __shfl(h1, k, 16);
        float ak = __shfl(ae, k, 16);
        xv += hk * Wm2[k * HF + f];
        hb += hk * Ws2[k * HF + f];
        hb += ak * Wm2[(HF + k) * HF + f];
    }
    xt2[idx]    = xv;
    h2base[idx] = hb;
}

// ---------------- edge pass 2: agg2[dst] += xt2[src] + b2 ----------------
__global__ __launch_bounds__(256) void k_edge2(const int* __restrict__ src, const int* __restrict__ dst,
                                               const float* __restrict__ xt2, const float* __restrict__ b2,
                                               int E, float* __restrict__ agg2) {
    long long t = (long long)blockIdx.x * blockDim.x + threadIdx.x;
    int e = (int)(t >> 4), f = (int)(t & 15);
    if (e >= E) return;
    int s = src[e], d = dst[e];
    float xv = xt2[(size_t)s * HF + f] + b2[f];
    atomAddF(agg2 + (size_t)d * HF + f, xv);
}

// ---------------- node pass 2: out = (agg2 + h2base) @ W3 + b3 ----------------
// wave per node; lane = output feature (64); lanes 0..15 hold h2 row, broadcast via shfl
__global__ __launch_bounds__(256) void k_node3(const float* __restrict__ agg2, const float* __restrict__ h2base,
                                               const float* __restrict__ W3, const float* __restrict__ b3,
                                               int N, float* __restrict__ out) {
    int lane = threadIdx.x & 63;
    int node = (int)((blockIdx.x * blockDim.x + threadIdx.x) >> 6);
    if (node >= N) return;
    float h2 = 0.f;
    if (lane < HF) {
        size_t idx = (size_t)node * HF + lane;
        h2 = agg2[idx] + h2base[idx];
    }
    float o = b3[lane];
#pragma unroll
    for (int k = 0; k < HF; k++) {
        o += __shfl(h2, k, 64) * W3[k * D_INF + lane];
    }
    out[(size_t)node * D_INF + lane] = o;
}

// ---------------- launch ----------------

static inline size_t align256(size_t x) { return (x + 255) & ~(size_t)255; }

extern "C" void kernel_launch(void* const* d_in, const int* in_sizes, int n_in,
                              void* d_out, int out_size, void* d_ws, size_t ws_size,
                              hipStream_t stream) {
    const float* x    = (const float*)d_in[0];
    const int*   ei   = (const int*)d_in[1];
    const float* eatt = (const float*)d_in[2];
    const float* Wm1  = (const float*)d_in[3];
    const float* b1   = (const float*)d_in[4];
    const float* Ws1  = (const float*)d_in[5];
    const float* bs1  = (const float*)d_in[6];
    const float* Wm2  = (const float*)d_in[7];
    const float* b2   = (const float*)d_in[8];
    const float* Ws2  = (const float*)d_in[9];
    const float* bs2  = (const float*)d_in[10];
    const float* W3   = (const float*)d_in[11];
    const float* b3   = (const float*)d_in[12];
    float* out = (float*)d_out;

    int N = in_sizes[0] / D_INF;
    int E = in_sizes[1] / 2;
    const int* src = ei;
    const int* dst = ei + E;

    char* ws = (char*)d_ws;
    size_t off = 0;
    auto alloc = [&](size_t bytes) -> void* { void* p = ws + off; off = align256(off + bytes); return p; };

    size_t szA = (size_t)N * HF * sizeof(float);
    float* aggm   = (float*)alloc(3 * szA);       // aggm | agge | agg2 contiguous -> single memset
    float* agge   = aggm + (size_t)N * HF;
    float* agg2   = agge + (size_t)N * HF;
    float* xt1    = (float*)alloc(szA);
    float* s1     = (float*)alloc(szA);
    float* xt2    = (float*)alloc(szA);
    float* h2base = (float*)alloc(szA);
    (void)ws_size; (void)n_in; (void)out_size;

    hipMemsetAsync(aggm, 0, 3 * szA, stream);

    dim3 blk(256);
    int gN16 = (N * HF + 255) / 256;                      // (node, feature) kernels
    long long tE = (long long)E * HF;                     // (edge, feature) kernels
    int gE16 = (int)((tE + 255) / 256);

    k_prep <<<dim3(gN16), blk, 0, stream>>>(x, Wm1, Ws1, bs1, N, xt1, s1);
    k_edge1<<<dim3(gE16), blk, 0, stream>>>(src, dst, xt1, eatt, b1, E, aggm, agge);
    k_node1<<<dim3(gN16), blk, 0, stream>>>(aggm, agge, s1, Wm1, Wm2, Ws2, bs2, N, xt2, h2base);
    k_edge2<<<dim3(gE16), blk, 0, stream>>>(src, dst, xt2, b2, E, agg2);
    k_node3<<<dim3((N + 3) / 4), blk, 0, stream>>>(agg2, h2base, W3, b3, N, out);
}